// Round 2
// baseline (512.810 us; speedup 1.0000x reference)
//
#include <hip/hip_runtime.h>

typedef unsigned short u16;
typedef __bf16 bf16x8 __attribute__((ext_vector_type(8)));
typedef u16   u16x8  __attribute__((ext_vector_type(8)));
typedef u16   u16x4  __attribute__((ext_vector_type(4)));
typedef float f32x4  __attribute__((ext_vector_type(4)));

// packed row layout: per batch, modality rows at OFFS[m], total RPB rows/batch
#define RPB 5084
#define SL0 2048
#define SL1 1024
#define SL2 1500
#define SL3 512

// ---------- helpers ----------
__device__ __forceinline__ u16 f2bf(float f) {
  union { float f; unsigned u; } x; x.f = f;
  unsigned u = x.u;
  u += 0x7fffu + ((u >> 16) & 1u);   // RNE
  return (u16)(u >> 16);
}
__device__ __forceinline__ float bf2f(u16 h) {
  union { unsigned u; float f; } x; x.u = ((unsigned)h) << 16;
  return x.f;
}
// async global->LDS, 16B per lane; dest = wave-uniform base + lane*16
__device__ __forceinline__ void gll16(const u16* g, u16* l) {
  __builtin_amdgcn_global_load_lds(
      (const __attribute__((address_space(1))) void*)g,
      (__attribute__((address_space(3))) void*)l, 16, 0, 0);
}

// LDS chunk layout (all GEMMs): each 16-row x 32-k tile is a 1024B chunk
// stored [oct][row] (oct = k/8). Stage lane L fetches global (row base+(L&15),
// k-oct L>>4) -> lands at chunk_base + L*16. MFMA fragment read for lane L
// needs exactly (row L&15, oct L>>4) -> ds_read_b128 at chunk_base + lane*16:
// fully linear wave64 read, ZERO bank conflicts (was 8-way at [row][32] layout).

// ---------- fused fp32 -> bf16 conversion, 12 segments, one launch ----------
#define NSEG 12
struct CvtSegs {
  const float* src[NSEG];
  u16*         dst[NSEG];
  int          blk_end[NSEG];
  int          blk_base[NSEG];
};
__global__ __launch_bounds__(256) void cvt_multi(CvtSegs segs) {
  int blk = blockIdx.x, seg = 0;
#pragma unroll
  for (int s = 0; s < NSEG; ++s) if (blk >= segs.blk_end[s]) seg = s + 1;
  const float* src = segs.src[seg];
  u16* dst = segs.dst[seg];
  int i = (blk - segs.blk_base[seg]) * 1024 + threadIdx.x * 4;
  f32x4 v = *(const f32x4*)(src + i);
  u16x4 o;
  o[0] = f2bf(v[0]); o[1] = f2bf(v[1]); o[2] = f2bf(v[2]); o[3] = f2bf(v[3]);
  *(u16x4*)(dst + i) = o;
}

// ---------- m97-style bf16 GEMM via global_load_lds (output GEMM) ----------
template<int STORE_F32>
__global__ __launch_bounds__(256) void gemm_lds(
    const u16* __restrict__ A,
    const u16* __restrict__ B0, const u16* __restrict__ B1, const u16* __restrict__ B2,
    const float* __restrict__ c0, const float* __restrict__ c1, const float* __restrict__ c2,
    void* __restrict__ Cout, int Mr, int K, int ldc)
{
  __shared__ u16 lA0[128 * 32], lA1[128 * 32];
  __shared__ u16 lB0[128 * 32], lB1[128 * 32];
  const int tid  = threadIdx.x;
  const int lane = tid & 63;
  const int wave = tid >> 6;
  const int wr   = (wave >> 1) * 64;
  const int wc   = (wave & 1) * 64;
  const int row0 = blockIdx.y * 128;

  const int wsel = blockIdx.x >> 3;
  const int colL = (blockIdx.x & 7) * 128;
  const u16*   Bw   = (wsel == 0) ? B0 : (wsel == 1) ? B1 : B2;
  const float* bias = (wsel == 0) ? c0 : (wsel == 1) ? c1 : c2;

  // conflict-free stage mapping: lane -> (row lane&15, k-oct lane>>4)
  const int srow = lane & 15;
  const int soct = (lane >> 4) * 8;
  int ra0 = row0 + wave * 32 + srow;      if (ra0 >= Mr) ra0 = Mr - 1;
  int ra1 = row0 + wave * 32 + srow + 16; if (ra1 >= Mr) ra1 = Mr - 1;
  const u16* pA0 = A + (size_t)ra0 * K + soct;
  const u16* pA1 = A + (size_t)ra1 * K + soct;
  const u16* pB0 = Bw + (size_t)(colL + wave * 32 + srow) * K + soct;
  const u16* pB1 = pB0 + (size_t)16 * K;
  u16* dA0a = &lA0[(wave * 32) * 32];      u16* dA1a = &lA0[(wave * 32 + 16) * 32];
  u16* dA0b = &lA1[(wave * 32) * 32];      u16* dA1b = &lA1[(wave * 32 + 16) * 32];
  u16* dB0a = &lB0[(wave * 32) * 32];      u16* dB1a = &lB0[(wave * 32 + 16) * 32];
  u16* dB0b = &lB1[(wave * 32) * 32];      u16* dB1b = &lB1[(wave * 32 + 16) * 32];

  f32x4 acc[4][4];
#pragma unroll
  for (int i = 0; i < 4; ++i)
#pragma unroll
    for (int j = 0; j < 4; ++j) acc[i][j] = f32x4{0.f, 0.f, 0.f, 0.f};

  const int la8 = lane * 8;
  const int ca  = (wr >> 4) * 512;   // A chunk base (u16) for this wave
  const int cbb = (wc >> 4) * 512;   // B chunk base (u16)

  for (int k0 = 0; k0 < K; k0 += 64) {
    __syncthreads();
    gll16(pA0 + k0, dA0a);       gll16(pA1 + k0, dA1a);
    gll16(pB0 + k0, dB0a);       gll16(pB1 + k0, dB1a);
    gll16(pA0 + k0 + 32, dA0b);  gll16(pA1 + k0 + 32, dA1b);
    gll16(pB0 + k0 + 32, dB0b);  gll16(pB1 + k0 + 32, dB1b);
    __syncthreads();

    bf16x8 af[4], bfr[4];
#pragma unroll
    for (int i = 0; i < 4; ++i)
      af[i] = *(const bf16x8*)&lA0[ca + i * 512 + la8];
#pragma unroll
    for (int j = 0; j < 4; ++j)
      bfr[j] = *(const bf16x8*)&lB0[cbb + j * 512 + la8];
#pragma unroll
    for (int i = 0; i < 4; ++i)
#pragma unroll
      for (int j = 0; j < 4; ++j)
        acc[i][j] = __builtin_amdgcn_mfma_f32_16x16x32_bf16(af[i], bfr[j], acc[i][j], 0, 0, 0);
#pragma unroll
    for (int i = 0; i < 4; ++i)
      af[i] = *(const bf16x8*)&lA1[ca + i * 512 + la8];
#pragma unroll
    for (int j = 0; j < 4; ++j)
      bfr[j] = *(const bf16x8*)&lB1[cbb + j * 512 + la8];
#pragma unroll
    for (int i = 0; i < 4; ++i)
#pragma unroll
      for (int j = 0; j < 4; ++j)
        acc[i][j] = __builtin_amdgcn_mfma_f32_16x16x32_bf16(af[i], bfr[j], acc[i][j], 0, 0, 0);
  }

  // epilogue: C/D layout col = lane&15, row = (lane>>4)*4 + reg  [m89/m91]
  const int fc = lane & 15;
  const int rq = (lane >> 4) * 4;
#pragma unroll
  for (int i = 0; i < 4; ++i) {
#pragma unroll
    for (int j = 0; j < 4; ++j) {
      const int cl = wc + j * 16 + fc;
      const float badd = bias[colL + cl];
      const int gc = blockIdx.x * 128 + cl;
#pragma unroll
      for (int reg = 0; reg < 4; ++reg) {
        int gr = row0 + wr + i * 16 + rq + reg;
        if (gr < Mr) {
          float v = acc[i][j][reg] + badd;
          if (STORE_F32) ((float*)Cout)[(size_t)gr * ldc + gc] = v;
          else           ((u16*)Cout)[(size_t)gr * ldc + gc] = f2bf(v);
        }
      }
    }
  }
}

// ---------- 256^2-tile deep-pipelined QKV GEMM (T3+T4+T5+T2-linear) ----------
// 8 waves (2M x 4N), per-wave C = 128x64. BK=32. 4-deep LDS ring:
// 4 slots x (A[256][32] + B[256][32]) u16 = 128 KiB. Counted vmcnt(8)
// (2 tiles in flight), ONE raw s_barrier per K-step, setprio around the
// 32-MFMA cluster. LDS chunks are [oct][row] so fragment reads are linear
// ds_read_b128 (zero bank conflicts).
__global__ __launch_bounds__(512, 2) void gemm_qkv_256(
    const u16* __restrict__ A,
    const u16* __restrict__ B0, const u16* __restrict__ B1, const u16* __restrict__ B2,
    const float* __restrict__ c0, const float* __restrict__ c1, const float* __restrict__ c2,
    u16* __restrict__ C, int Mr, int K)
{
  __shared__ u16 lds[4][2][8192];          // [slot][A/B][16 chunks x 512]
  const int tid  = threadIdx.x;
  const int lane = tid & 63;
  const int wave = tid >> 6;
  const int wm   = wave >> 2;              // 0..1
  const int wn   = wave & 3;               // 0..3
  const int row0 = blockIdx.y * 256;
  const int cb   = blockIdx.x;             // 0..11
  const int wsel = cb >> 2;
  const int colL = (cb & 3) * 256;
  const u16*   Bw   = (wsel == 0) ? B0 : (wsel == 1) ? B1 : B2;
  const float* bias = (wsel == 0) ? c0 : (wsel == 1) ? c1 : c2;

  // conflict-free stage mapping: lane -> (row lane&15, k-oct lane>>4)
  const int srow = lane & 15;
  const int soct = (lane >> 4) * 8;
  int ra0 = row0 + wave * 16 + srow;        if (ra0 >= Mr) ra0 = Mr - 1;
  int ra1 = row0 + 128 + wave * 16 + srow;  if (ra1 >= Mr) ra1 = Mr - 1;
  const u16* pA0 = A + (size_t)ra0 * K + soct;
  const u16* pA1 = A + (size_t)ra1 * K + soct;
  const u16* pB0 = Bw + (size_t)(colL + wave * 16 + srow) * K + soct;
  const u16* pB1 = pB0 + (size_t)128 * K;
  const int NS = K >> 5;                    // K-steps of 32

#define QSTAGE(slot, k0) do {                                   \
    gll16(pA0 + (k0), (u16*)&lds[slot][0][wave * 512]);         \
    gll16(pA1 + (k0), (u16*)&lds[slot][0][4096 + wave * 512]);  \
    gll16(pB0 + (k0), (u16*)&lds[slot][1][wave * 512]);         \
    gll16(pB1 + (k0), (u16*)&lds[slot][1][4096 + wave * 512]);  \
  } while (0)

  f32x4 acc[8][4];
#pragma unroll
  for (int m = 0; m < 8; ++m)
#pragma unroll
    for (int n = 0; n < 4; ++n) acc[m][n] = f32x4{0.f, 0.f, 0.f, 0.f};

  // prologue: 3 tiles in flight (12 VMEM items/wave)
  QSTAGE(0, 0);
  QSTAGE(1, 32);
  QSTAGE(2, 64);

  const int la8 = lane * 8;
  const int cam = wm * 8 * 512;            // A chunk base (u16)
  const int cbn = wn * 4 * 512;            // B chunk base (u16)

#pragma unroll 4
  for (int s = 0; s < NS; ++s) {
    // certify tile s landed: keep tiles s+1, s+2 (8 items) in flight
    asm volatile("s_waitcnt vmcnt(8)" ::: "memory");
    __builtin_amdgcn_s_barrier();

    const u16* Ab = &lds[s & 3][0][0];
    const u16* Bb = &lds[s & 3][1][0];
    bf16x8 af[8], bf[4];
#pragma unroll
    for (int m = 0; m < 8; ++m)
      af[m] = *(const bf16x8*)&Ab[cam + m * 512 + la8];
#pragma unroll
    for (int n = 0; n < 4; ++n)
      bf[n] = *(const bf16x8*)&Bb[cbn + n * 512 + la8];

    // prefetch tile s+3 into slot (s-1)&3 (freed by the barrier above);
    // past the end: dummy re-stage of the last tile into a never-read slot
    // keeps the vmcnt count uniform (L2-hot, negligible traffic).
    const int s3 = s + 3;
    const int k3 = (s3 < NS ? s3 : NS - 1) << 5;
    QSTAGE(s3 & 3, k3);

    asm volatile("s_waitcnt lgkmcnt(0)" ::: "memory");
    __builtin_amdgcn_sched_barrier(0);     // rule 18: keep MFMA below the wait
    __builtin_amdgcn_s_setprio(1);
#pragma unroll
    for (int m = 0; m < 8; ++m)
#pragma unroll
      for (int n = 0; n < 4; ++n)
        acc[m][n] = __builtin_amdgcn_mfma_f32_16x16x32_bf16(af[m], bf[n], acc[m][n], 0, 0, 0);
    __builtin_amdgcn_s_setprio(0);
  }
#undef QSTAGE

  // drain in-flight LDS writes before the workgroup can exit
  asm volatile("s_waitcnt vmcnt(0)" ::: "memory");

  // epilogue: C/D layout col = lane&15, row = (lane>>4)*4 + reg
  const int fc = lane & 15;
  const int rq = (lane >> 4) * 4;
#pragma unroll
  for (int m = 0; m < 8; ++m) {
#pragma unroll
    for (int n = 0; n < 4; ++n) {
      const int cl = wn * 64 + n * 16 + fc;
      const float badd = bias[colL + cl];
      const int gc = cb * 256 + cl;
#pragma unroll
      for (int reg = 0; reg < 4; ++reg) {
        int gr = row0 + wm * 128 + m * 16 + rq + reg;
        if (gr < Mr)
          C[(size_t)gr * 3072 + gc] = f2bf(acc[m][n][reg] + badd);
      }
    }
  }
}

// ---------- ALL projections in ONE launch (segment table, longest-K first) ----------
struct ProjSegs {
  const u16*   A[4];
  const u16*   Bw[4];
  const float* b0[4];
  const float* b1[4];
  int Mr[4], K[4], sl[4], obase[4];
  int blk_end[4];
};
__global__ __launch_bounds__(256) void gemm_proj_all(ProjSegs ps, u16* __restrict__ Cout) {
  int blk = blockIdx.x, seg = 0;
#pragma unroll
  for (int s = 0; s < 3; ++s) if (blk >= ps.blk_end[s]) seg = s + 1;
  const int base  = seg ? ps.blk_end[seg - 1] : 0;
  const int local = blk - base;
  const int row0  = (local >> 3) * 128;
  const int col0  = (local & 7) * 128;
  const int Mr = ps.Mr[seg], K = ps.K[seg], sl = ps.sl[seg], obase = ps.obase[seg];
  const u16* A  = ps.A[seg];
  const u16* Bw = ps.Bw[seg];
  const float* bias0 = ps.b0[seg];
  const float* bias1 = ps.b1[seg];

  __shared__ u16 lA0[128 * 32], lA1[128 * 32];
  __shared__ u16 lB0[128 * 32], lB1[128 * 32];
  const int tid  = threadIdx.x;
  const int lane = tid & 63;
  const int wave = tid >> 6;
  const int wr   = (wave >> 1) * 64;
  const int wc   = (wave & 1) * 64;

  // conflict-free stage mapping: lane -> (row lane&15, k-oct lane>>4)
  const int srow = lane & 15;
  const int soct = (lane >> 4) * 8;
  int ra0 = row0 + wave * 32 + srow;      if (ra0 >= Mr) ra0 = Mr - 1;
  int ra1 = row0 + wave * 32 + srow + 16; if (ra1 >= Mr) ra1 = Mr - 1;
  const u16* pA0 = A + (size_t)ra0 * K + soct;
  const u16* pA1 = A + (size_t)ra1 * K + soct;
  const u16* pB0 = Bw + (size_t)(col0 + wave * 32 + srow) * K + soct;
  const u16* pB1 = pB0 + (size_t)16 * K;
  u16* dA0a = &lA0[(wave * 32) * 32];      u16* dA1a = &lA0[(wave * 32 + 16) * 32];
  u16* dA0b = &lA1[(wave * 32) * 32];      u16* dA1b = &lA1[(wave * 32 + 16) * 32];
  u16* dB0a = &lB0[(wave * 32) * 32];      u16* dB1a = &lB0[(wave * 32 + 16) * 32];
  u16* dB0b = &lB1[(wave * 32) * 32];      u16* dB1b = &lB1[(wave * 32 + 16) * 32];

  f32x4 acc[4][4];
#pragma unroll
  for (int i = 0; i < 4; ++i)
#pragma unroll
    for (int j = 0; j < 4; ++j) acc[i][j] = f32x4{0.f, 0.f, 0.f, 0.f};

  const int la8 = lane * 8;
  const int ca  = (wr >> 4) * 512;
  const int cbb = (wc >> 4) * 512;

  for (int k0 = 0; k0 < K; k0 += 64) {
    __syncthreads();
    gll16(pA0 + k0, dA0a);       gll16(pA1 + k0, dA1a);
    gll16(pB0 + k0, dB0a);       gll16(pB1 + k0, dB1a);
    gll16(pA0 + k0 + 32, dA0b);  gll16(pA1 + k0 + 32, dA1b);
    gll16(pB0 + k0 + 32, dB0b);  gll16(pB1 + k0 + 32, dB1b);
    __syncthreads();

    bf16x8 af[4], bfr[4];
#pragma unroll
    for (int i = 0; i < 4; ++i)
      af[i] = *(const bf16x8*)&lA0[ca + i * 512 + la8];
#pragma unroll
    for (int j = 0; j < 4; ++j)
      bfr[j] = *(const bf16x8*)&lB0[cbb + j * 512 + la8];
#pragma unroll
    for (int i = 0; i < 4; ++i)
#pragma unroll
      for (int j = 0; j < 4; ++j)
        acc[i][j] = __builtin_amdgcn_mfma_f32_16x16x32_bf16(af[i], bfr[j], acc[i][j], 0, 0, 0);
#pragma unroll
    for (int i = 0; i < 4; ++i)
      af[i] = *(const bf16x8*)&lA1[ca + i * 512 + la8];
#pragma unroll
    for (int j = 0; j < 4; ++j)
      bfr[j] = *(const bf16x8*)&lB1[cbb + j * 512 + la8];
#pragma unroll
    for (int i = 0; i < 4; ++i)
#pragma unroll
      for (int j = 0; j < 4; ++j)
        acc[i][j] = __builtin_amdgcn_mfma_f32_16x16x32_bf16(af[i], bfr[j], acc[i][j], 0, 0, 0);
  }

  const int fc = lane & 15;
  const int rq = (lane >> 4) * 4;
#pragma unroll
  for (int i = 0; i < 4; ++i) {
#pragma unroll
    for (int j = 0; j < 4; ++j) {
      const int c = col0 + wc + j * 16 + fc;
      const float badd = bias0[c] + bias1[c];
#pragma unroll
      for (int reg = 0; reg < 4; ++reg) {
        int gr = row0 + wr + i * 16 + rq + reg;
        if (gr < Mr) {
          int bb = gr / sl, ss = gr - bb * sl;
          Cout[(size_t)(bb * RPB + obase + ss) * 1024 + c] = f2bf(acc[i][j][reg] + badd);
        }
      }
    }
  }
}

// ---------- windowed attention + mean over modalities ----------
// ROUTES (IEEE-tie-corrected Cantor): m0:[0,1,2] m1:[0,1,2] m2:[2,3,0] m3:[3,2,0]
__global__ __launch_bounds__(256) void attn_fuse(
    const u16* __restrict__ QKV,   // [RROWS][3072]: Q|K|V
    u16* __restrict__ fused,
    const float* __restrict__ bq, const float* __restrict__ bk, const float* __restrict__ bv,
    const float* __restrict__ temp_ptr)
{
  const int ROUTE[4][3] = {{0,1,2},{0,1,2},{2,3,0},{3,2,0}};
  const int SLm[4]  = {SL0, SL1, SL2, SL3};
  const int OFFS[4] = {0, 2048, 3072, 4572};
  const int tid  = threadIdx.x;
  const int lane = tid & 63;
  const int wave = tid >> 6;
  const int bs   = blockIdx.x * 2 + (wave >> 1);
  const int s    = bs & 2047;
  const int b    = bs >> 11;
  const int h    = (wave & 1) * 8 + (lane >> 3);
  const int sub  = lane & 7;
  const int dbase = h * 64 + sub * 8;
  const float scale = 1.0f / (8.0f * fabsf(temp_ptr[0]));

  float qf[4][8], kf[4][8], vf[4][8];
#pragma unroll
  for (int r = 0; r < 4; ++r) {
    if (s < SLm[r]) {
      const u16* base = QKV + ((size_t)(b * RPB + OFFS[r] + s)) * 3072 + dbase;
      u16x8 q8 = *(const u16x8*)(base);
      u16x8 k8 = *(const u16x8*)(base + 1024);
      u16x8 v8 = *(const u16x8*)(base + 2048);
#pragma unroll
      for (int i = 0; i < 8; ++i) {
        qf[r][i] = bf2f(q8[i]); kf[r][i] = bf2f(k8[i]); vf[r][i] = bf2f(v8[i]);
      }
    } else {
#pragma unroll
      for (int i = 0; i < 8; ++i) {
        qf[r][i] = bq[dbase + i]; kf[r][i] = bk[dbase + i]; vf[r][i] = bv[dbase + i];
      }
    }
  }

  float acc[8];
#pragma unroll
  for (int i = 0; i < 8; ++i) acc[i] = 0.f;

#pragma unroll
  for (int m = 0; m < 4; ++m) {
    float sc[3];
#pragma unroll
    for (int w = 0; w < 3; ++w) {
      const int r = ROUTE[m][w];
      float d = 0.f;
#pragma unroll
      for (int i = 0; i < 8; ++i) d += qf[m][i] * kf[r][i];
      d += __shfl_xor(d, 1, 64);
      d += __shfl_xor(d, 2, 64);
      d += __shfl_xor(d, 4, 64);
      sc[w] = d * scale;
    }
    float mx = fmaxf(sc[0], fmaxf(sc[1], sc[2]));
    float e0 = __expf(sc[0] - mx), e1 = __expf(sc[1] - mx), e2 = __expf(sc[2] - mx);
    float inv = 1.0f / (e0 + e1 + e2);
    float ws[3] = {e0 * inv, e1 * inv, e2 * inv};
#pragma unroll
    for (int w = 0; w < 3; ++w) {
      const int r = ROUTE[m][w];
#pragma unroll
      for (int i = 0; i < 8; ++i) acc[i] += ws[w] * vf[r][i];
    }
  }
  u16x8 o;
#pragma unroll
  for (int i = 0; i < 8; ++i) o[i] = f2bf(acc[i] * 0.25f);
  *(u16x8*)(fused + (size_t)bs * 1024 + dbase) = o;
}

// ---------- host orchestration ----------
extern "C" void kernel_launch(void* const* d_in, const int* in_sizes, int n_in,
                              void* d_out, int out_size, void* d_ws, size_t ws_size,
                              hipStream_t stream) {
  const int B = 4, S = 2048, D = 1024;
  const int SL[4]   = {SL0, SL1, SL2, SL3};
  const int DIM[4]  = {768, 1024, 512, 2048};
  const int OFFS[4] = {0, 2048, 3072, 4572};

  const float* x[4]  = {(const float*)d_in[0], (const float*)d_in[3], (const float*)d_in[6], (const float*)d_in[9]};
  const float* Wm[4] = {(const float*)d_in[1], (const float*)d_in[4], (const float*)d_in[7], (const float*)d_in[10]};
  const float* bm[4] = {(const float*)d_in[2], (const float*)d_in[5], (const float*)d_in[8], (const float*)d_in[11]};
  const float* mod_emb = (const float*)d_in[12];
  const float* Wq = (const float*)d_in[13]; const float* bq = (const float*)d_in[14];
  const float* Wk = (const float*)d_in[15]; const float* bk = (const float*)d_in[16];
  const float* Wv = (const float*)d_in[17]; const float* bv = (const float*)d_in[18];
  const float* Wo = (const float*)d_in[19]; const float* bo = (const float*)d_in[20];
  const float* temp = (const float*)d_in[21];

  const int RROWS = B * RPB;                 // 20336 real rows
  const size_t stackedB = ((size_t)RROWS * D * 2 + 255) / 256 * 256;
  const size_t qkvB     = ((size_t)RROWS * 3 * D * 2 + 255) / 256 * 256;
  const size_t wB       = ((size_t)D * D * 2 + 255) / 256 * 256;
  size_t wmB[4];
  for (int m = 0; m < 4; ++m) wmB[m] = ((size_t)D * DIM[m] * 2 + 255) / 256 * 256;
  const size_t need = stackedB + qkvB + 4 * wB + wmB[0] + wmB[1] + wmB[2] + wmB[3];
  if (ws_size < need) return;                // clean failure, not OOB crash

  char* p = (char*)d_ws;
  u16* stacked = (u16*)p;  p += stackedB;
  char* qkvbase = p;
  u16* qkv     = (u16*)p;  p += qkvB;
  u16* wqb     = (u16*)p;  p += wB;
  u16* wkb     = (u16*)p;  p += wB;
  u16* wvb     = (u16*)p;  p += wB;
  u16* wob     = (u16*)p;  p += wB;
  u16* wmb[4];
  for (int m = 0; m < 4; ++m) { wmb[m] = (u16*)p; p += wmB[m]; }
  u16* fusedb  = stacked;  // stacked dead after QKV GEMM

  // bf16 activations overlaid in the not-yet-live qkv buffer
  u16* xb[4];
  {
    char* q = qkvbase;
    for (int m = 0; m < 4; ++m) {
      xb[m] = (u16*)q;
      q += ((size_t)B * SL[m] * DIM[m] * 2 + 255) / 256 * 256;
    }
  }

  // single fused fp32->bf16 conversion
  {
    CvtSegs cs;
    const float* srcs[NSEG] = {x[0], x[1], x[2], x[3], Wm[0], Wm[1], Wm[2], Wm[3], Wq, Wk, Wv, Wo};
    u16* dsts[NSEG] = {xb[0], xb[1], xb[2], xb[3], wmb[0], wmb[1], wmb[2], wmb[3], wqb, wkb, wvb, wob};
    int ns[NSEG];
    for (int m = 0; m < 4; ++m) ns[m] = B * SL[m] * DIM[m];
    for (int m = 0; m < 4; ++m) ns[4 + m] = D * DIM[m];
    for (int i = 0; i < 4; ++i) ns[8 + i] = D * D;
    int base = 0;
    for (int i = 0; i < NSEG; ++i) {
      cs.src[i] = srcs[i]; cs.dst[i] = dsts[i];
      cs.blk_base[i] = base;
      base += (ns[i] + 1023) / 1024;
      cs.blk_end[i] = base;
    }
    cvt_multi<<<base, 256, 0, stream>>>(cs);
  }

  // ALL projections, one launch, longest-K segment first (video,image,text,audio)
  {
    const int ord[4] = {3, 1, 0, 2};   // by descending K: 2048,1024,768,512
    ProjSegs ps;
    int base = 0;
    for (int i = 0; i < 4; ++i) {
      int m = ord[i];
      int Mr = B * SL[m];
      ps.A[i] = xb[m]; ps.Bw[i] = wmb[m];
      ps.b0[i] = bm[m]; ps.b1[i] = mod_emb + m * D;
      ps.Mr[i] = Mr; ps.K[i] = DIM[m]; ps.sl[i] = SL[m]; ps.obase[i] = OFFS[m];
      base += 8 * ((Mr + 127) / 128);
      ps.blk_end[i] = base;
    }
    gemm_proj_all<<<base, 256, 0, stream>>>(ps, stacked);
  }

  // fused Q|K|V GEMM: [20336 x 3072] = stacked @ [Wq|Wk|Wv]^T
  // 256^2-tile deep-pipelined kernel (counted vmcnt, 1 barrier/K-step)
  {
    dim3 grid(12, (RROWS + 255) / 256);
    gemm_qkv_256<<<grid, 512, 0, stream>>>(stacked, wqb, wkb, wvb, bq, bk, bv,
                                           qkv, RROWS, D);
  }

  // attention over window + mean over modalities -> fused (bf16)
  attn_fuse<<<(B * S) / 2, 256, 0, stream>>>(qkv, fusedb, bq, bk, bv, temp);

  // output GEMM: (B*S) x D, fp32 out
  {
    dim3 grid(8, (B * S) / 128);
    gemm_lds<1><<<grid, 256, 0, stream>>>(fusedb, wob, wob, wob, bo, bo, bo,
                                          d_out, B * S, D, D);
  }
}

// Round 3
// 470.384 us; speedup vs baseline: 1.0902x; 1.0902x over previous
//
#include <hip/hip_runtime.h>

typedef unsigned short u16;
typedef __bf16 bf16x8 __attribute__((ext_vector_type(8)));
typedef u16   u16x8  __attribute__((ext_vector_type(8)));
typedef u16   u16x4  __attribute__((ext_vector_type(4)));
typedef float f32x4  __attribute__((ext_vector_type(4)));

// packed row layout: per batch, modality rows at OFFS[m], total RPB rows/batch
#define RPB 5084
#define SL0 2048
#define SL1 1024
#define SL2 1500
#define SL3 512

// ---------- helpers ----------
__device__ __forceinline__ u16 f2bf(float f) {
  union { float f; unsigned u; } x; x.f = f;
  unsigned u = x.u;
  u += 0x7fffu + ((u >> 16) & 1u);   // RNE
  return (u16)(u >> 16);
}
__device__ __forceinline__ float bf2f(u16 h) {
  union { unsigned u; float f; } x; x.u = ((unsigned)h) << 16;
  return x.f;
}
// async global->LDS, 16B per lane; dest = wave-uniform base + lane*16
__device__ __forceinline__ void gll16(const u16* g, u16* l) {
  __builtin_amdgcn_global_load_lds(
      (const __attribute__((address_space(1))) void*)g,
      (__attribute__((address_space(3))) void*)l, 16, 0, 0);
}

// LDS chunk layout (all GEMMs): each 16-row x 32-k tile is a 1024B chunk.
// Stage lane s fetches global (row s>>2, k-oct (s&3)^((s>>3)&3)) -> lands at
// chunk_base + s*16. Quad s=4q..4q+3 covers one row's 64B contiguously (same
// address set, lane-permuted) -> full coalescing. Fragment read for lane L
// (row L&15, oct L>>4) sits at u16 offset 32*(L&15) + 8*((L>>4)^(((L&15)>>1)&3));
// every 8 consecutive read lanes hit 8 distinct bank-quads -> ZERO conflicts.

// ---------- fused fp32 -> bf16 conversion, 12 segments, one launch ----------
#define NSEG 12
struct CvtSegs {
  const float* src[NSEG];
  u16*         dst[NSEG];
  int          blk_end[NSEG];
  int          blk_base[NSEG];
};
__global__ __launch_bounds__(256) void cvt_multi(CvtSegs segs) {
  int blk = blockIdx.x, seg = 0;
#pragma unroll
  for (int s = 0; s < NSEG; ++s) if (blk >= segs.blk_end[s]) seg = s + 1;
  const float* src = segs.src[seg];
  u16* dst = segs.dst[seg];
  int i = (blk - segs.blk_base[seg]) * 1024 + threadIdx.x * 4;
  f32x4 v = *(const f32x4*)(src + i);
  u16x4 o;
  o[0] = f2bf(v[0]); o[1] = f2bf(v[1]); o[2] = f2bf(v[2]); o[3] = f2bf(v[3]);
  *(u16x4*)(dst + i) = o;
}

// ---------- m97-style bf16 GEMM via global_load_lds (output GEMM) ----------
template<int STORE_F32>
__global__ __launch_bounds__(256) void gemm_lds(
    const u16* __restrict__ A,
    const u16* __restrict__ B0, const u16* __restrict__ B1, const u16* __restrict__ B2,
    const float* __restrict__ c0, const float* __restrict__ c1, const float* __restrict__ c2,
    void* __restrict__ Cout, int Mr, int K, int ldc)
{
  __shared__ u16 lA0[128 * 32], lA1[128 * 32];
  __shared__ u16 lB0[128 * 32], lB1[128 * 32];
  const int tid  = threadIdx.x;
  const int lane = tid & 63;
  const int wave = tid >> 6;
  const int wr   = (wave >> 1) * 64;
  const int wc   = (wave & 1) * 64;
  const int row0 = blockIdx.y * 128;

  const int wsel = blockIdx.x >> 3;
  const int colL = (blockIdx.x & 7) * 128;
  const u16*   Bw   = (wsel == 0) ? B0 : (wsel == 1) ? B1 : B2;
  const float* bias = (wsel == 0) ? c0 : (wsel == 1) ? c1 : c2;

  // stage mapping: quad-contiguous global, XOR-permuted octet within quad
  const int srow = lane >> 2;
  const int soct = (((lane & 3) ^ ((lane >> 3) & 3))) << 3;
  int ra0 = row0 + wave * 32 + srow;      if (ra0 >= Mr) ra0 = Mr - 1;
  int ra1 = row0 + wave * 32 + srow + 16; if (ra1 >= Mr) ra1 = Mr - 1;
  const u16* pA0 = A + (size_t)ra0 * K + soct;
  const u16* pA1 = A + (size_t)ra1 * K + soct;
  const u16* pB0 = Bw + (size_t)(colL + wave * 32 + srow) * K + soct;
  const u16* pB1 = pB0 + (size_t)16 * K;
  u16* dA0a = &lA0[(wave * 32) * 32];      u16* dA1a = &lA0[(wave * 32 + 16) * 32];
  u16* dA0b = &lA1[(wave * 32) * 32];      u16* dA1b = &lA1[(wave * 32 + 16) * 32];
  u16* dB0a = &lB0[(wave * 32) * 32];      u16* dB1a = &lB0[(wave * 32 + 16) * 32];
  u16* dB0b = &lB1[(wave * 32) * 32];      u16* dB1b = &lB1[(wave * 32 + 16) * 32];

  f32x4 acc[4][4];
#pragma unroll
  for (int i = 0; i < 4; ++i)
#pragma unroll
    for (int j = 0; j < 4; ++j) acc[i][j] = f32x4{0.f, 0.f, 0.f, 0.f};

  // fragment read offset within a 512-u16 chunk (conflict-free)
  const int fr  = lane & 15;
  const int fo  = lane >> 4;
  const int lrd = fr * 32 + (((fo ^ ((fr >> 1) & 3))) << 3);
  const int ca  = (wr >> 4) * 512;   // A chunk base (u16) for this wave
  const int cbb = (wc >> 4) * 512;   // B chunk base (u16)

  for (int k0 = 0; k0 < K; k0 += 64) {
    __syncthreads();
    gll16(pA0 + k0, dA0a);       gll16(pA1 + k0, dA1a);
    gll16(pB0 + k0, dB0a);       gll16(pB1 + k0, dB1a);
    gll16(pA0 + k0 + 32, dA0b);  gll16(pA1 + k0 + 32, dA1b);
    gll16(pB0 + k0 + 32, dB0b);  gll16(pB1 + k0 + 32, dB1b);
    __syncthreads();

    bf16x8 af[4], bfr[4];
#pragma unroll
    for (int j = 0; j < 4; ++j)
      bfr[j] = *(const bf16x8*)&lB0[cbb + j * 512 + lrd];
#pragma unroll
    for (int i = 0; i < 4; ++i)
      af[i] = *(const bf16x8*)&lA0[ca + i * 512 + lrd];
#pragma unroll
    for (int i = 0; i < 4; ++i)
#pragma unroll
      for (int j = 0; j < 4; ++j)
        acc[i][j] = __builtin_amdgcn_mfma_f32_16x16x32_bf16(af[i], bfr[j], acc[i][j], 0, 0, 0);
#pragma unroll
    for (int j = 0; j < 4; ++j)
      bfr[j] = *(const bf16x8*)&lB1[cbb + j * 512 + lrd];
#pragma unroll
    for (int i = 0; i < 4; ++i)
      af[i] = *(const bf16x8*)&lA1[ca + i * 512 + lrd];
#pragma unroll
    for (int i = 0; i < 4; ++i)
#pragma unroll
      for (int j = 0; j < 4; ++j)
        acc[i][j] = __builtin_amdgcn_mfma_f32_16x16x32_bf16(af[i], bfr[j], acc[i][j], 0, 0, 0);
  }

  // epilogue: C/D layout col = lane&15, row = (lane>>4)*4 + reg  [m89/m91]
  const int fc = lane & 15;
  const int rq = (lane >> 4) * 4;
#pragma unroll
  for (int i = 0; i < 4; ++i) {
#pragma unroll
    for (int j = 0; j < 4; ++j) {
      const int cl = wc + j * 16 + fc;
      const float badd = bias[colL + cl];
      const int gc = blockIdx.x * 128 + cl;
#pragma unroll
      for (int reg = 0; reg < 4; ++reg) {
        int gr = row0 + wr + i * 16 + rq + reg;
        if (gr < Mr) {
          float v = acc[i][j][reg] + badd;
          if (STORE_F32) ((float*)Cout)[(size_t)gr * ldc + gc] = v;
          else           ((u16*)Cout)[(size_t)gr * ldc + gc] = f2bf(v);
        }
      }
    }
  }
}

// ---------- 256^2-tile deep-pipelined QKV GEMM ----------
// 8 waves (2M x 4N), per-wave C = 128x64. BK=32. 4-deep LDS ring, counted
// vmcnt(8), ONE raw s_barrier per K-step. ds_read->MFMA interleave is left
// to the compiler (fine-grained lgkmcnt): B frags read first so MFMA row m
// unblocks as af[m] arrives. Empty asm-memory-clobber after the barrier
// pins loads/stages below it (race safety without serializing).
__global__ __launch_bounds__(512, 2) void gemm_qkv_256(
    const u16* __restrict__ A,
    const u16* __restrict__ B0, const u16* __restrict__ B1, const u16* __restrict__ B2,
    const float* __restrict__ c0, const float* __restrict__ c1, const float* __restrict__ c2,
    u16* __restrict__ C, int Mr, int K)
{
  __shared__ u16 lds[4][2][8192];          // [slot][A/B][16 chunks x 512]
  const int tid  = threadIdx.x;
  const int lane = tid & 63;
  const int wave = tid >> 6;
  const int wm   = wave >> 2;              // 0..1
  const int wn   = wave & 3;               // 0..3
  const int row0 = blockIdx.y * 256;
  const int cb   = blockIdx.x;             // 0..11
  const int wsel = cb >> 2;
  const int colL = (cb & 3) * 256;
  const u16*   Bw   = (wsel == 0) ? B0 : (wsel == 1) ? B1 : B2;
  const float* bias = (wsel == 0) ? c0 : (wsel == 1) ? c1 : c2;

  // stage mapping: quad-contiguous global, XOR-permuted octet within quad
  const int srow = lane >> 2;
  const int soct = (((lane & 3) ^ ((lane >> 3) & 3))) << 3;
  int ra0 = row0 + wave * 16 + srow;        if (ra0 >= Mr) ra0 = Mr - 1;
  int ra1 = row0 + 128 + wave * 16 + srow;  if (ra1 >= Mr) ra1 = Mr - 1;
  const u16* pA0 = A + (size_t)ra0 * K + soct;
  const u16* pA1 = A + (size_t)ra1 * K + soct;
  const u16* pB0 = Bw + (size_t)(colL + wave * 16 + srow) * K + soct;
  const u16* pB1 = pB0 + (size_t)128 * K;
  const int NS = K >> 5;                    // K-steps of 32

#define QSTAGE(slot, k0) do {                                   \
    gll16(pA0 + (k0), (u16*)&lds[slot][0][wave * 512]);         \
    gll16(pA1 + (k0), (u16*)&lds[slot][0][4096 + wave * 512]);  \
    gll16(pB0 + (k0), (u16*)&lds[slot][1][wave * 512]);         \
    gll16(pB1 + (k0), (u16*)&lds[slot][1][4096 + wave * 512]);  \
  } while (0)

  f32x4 acc[8][4];
#pragma unroll
  for (int m = 0; m < 8; ++m)
#pragma unroll
    for (int n = 0; n < 4; ++n) acc[m][n] = f32x4{0.f, 0.f, 0.f, 0.f};

  // prologue: 3 tiles in flight (12 VMEM items/wave)
  QSTAGE(0, 0);
  QSTAGE(1, 32);
  QSTAGE(2, 64);

  // fragment read offset within a 512-u16 chunk (conflict-free)
  const int fr  = lane & 15;
  const int fo  = lane >> 4;
  const int lrd = fr * 32 + (((fo ^ ((fr >> 1) & 3))) << 3);
  const int cam = wm * 8 * 512;            // A chunk base (u16)
  const int cbn = wn * 4 * 512;            // B chunk base (u16)

#pragma unroll 4
  for (int s = 0; s < NS; ++s) {
    // certify tile s landed: keep tiles s+1, s+2 (8 items) in flight
    asm volatile("s_waitcnt vmcnt(8)" ::: "memory");
    __builtin_amdgcn_s_barrier();
    asm volatile("" ::: "memory");         // no loads/stages above the barrier

    const u16* Ab = &lds[s & 3][0][0];
    const u16* Bb = &lds[s & 3][1][0];
    bf16x8 af[8], bf[4];
#pragma unroll
    for (int n = 0; n < 4; ++n)
      bf[n] = *(const bf16x8*)&Bb[cbn + n * 512 + lrd];
#pragma unroll
    for (int m = 0; m < 8; ++m)
      af[m] = *(const bf16x8*)&Ab[cam + m * 512 + lrd];

    // prefetch tile s+3 into slot (s-1)&3 (freed by the barrier above);
    // past the end: dummy re-stage of the last tile into a never-read slot
    // keeps the vmcnt count uniform (L2-hot, negligible traffic).
    const int s3 = s + 3;
    const int k3 = (s3 < NS ? s3 : NS - 1) << 5;
    QSTAGE(s3 & 3, k3);

    // no lgkmcnt(0)/sched_barrier here: compiler emits fine-grained lgkmcnt
    // so MFMA row m starts as soon as bf[0..3] + af[m] have landed.
#pragma unroll
    for (int m = 0; m < 8; ++m)
#pragma unroll
      for (int n = 0; n < 4; ++n)
        acc[m][n] = __builtin_amdgcn_mfma_f32_16x16x32_bf16(af[m], bf[n], acc[m][n], 0, 0, 0);
  }
#undef QSTAGE

  // drain in-flight LDS writes before the workgroup can exit
  asm volatile("s_waitcnt vmcnt(0)" ::: "memory");

  // epilogue: C/D layout col = lane&15, row = (lane>>4)*4 + reg
  const int fc = lane & 15;
  const int rq = (lane >> 4) * 4;
#pragma unroll
  for (int m = 0; m < 8; ++m) {
#pragma unroll
    for (int n = 0; n < 4; ++n) {
      const int cl = wn * 64 + n * 16 + fc;
      const float badd = bias[colL + cl];
      const int gc = cb * 256 + cl;
#pragma unroll
      for (int reg = 0; reg < 4; ++reg) {
        int gr = row0 + wm * 128 + m * 16 + rq + reg;
        if (gr < Mr)
          C[(size_t)gr * 3072 + gc] = f2bf(acc[m][n][reg] + badd);
      }
    }
  }
}

// ---------- ALL projections in ONE launch (segment table, longest-K first) ----------
struct ProjSegs {
  const u16*   A[4];
  const u16*   Bw[4];
  const float* b0[4];
  const float* b1[4];
  int Mr[4], K[4], sl[4], obase[4];
  int blk_end[4];
};
__global__ __launch_bounds__(256) void gemm_proj_all(ProjSegs ps, u16* __restrict__ Cout) {
  int blk = blockIdx.x, seg = 0;
#pragma unroll
  for (int s = 0; s < 3; ++s) if (blk >= ps.blk_end[s]) seg = s + 1;
  const int base  = seg ? ps.blk_end[seg - 1] : 0;
  const int local = blk - base;
  const int row0  = (local >> 3) * 128;
  const int col0  = (local & 7) * 128;
  const int Mr = ps.Mr[seg], K = ps.K[seg], sl = ps.sl[seg], obase = ps.obase[seg];
  const u16* A  = ps.A[seg];
  const u16* Bw = ps.Bw[seg];
  const float* bias0 = ps.b0[seg];
  const float* bias1 = ps.b1[seg];

  __shared__ u16 lA0[128 * 32], lA1[128 * 32];
  __shared__ u16 lB0[128 * 32], lB1[128 * 32];
  const int tid  = threadIdx.x;
  const int lane = tid & 63;
  const int wave = tid >> 6;
  const int wr   = (wave >> 1) * 64;
  const int wc   = (wave & 1) * 64;

  // stage mapping: quad-contiguous global, XOR-permuted octet within quad
  const int srow = lane >> 2;
  const int soct = (((lane & 3) ^ ((lane >> 3) & 3))) << 3;
  int ra0 = row0 + wave * 32 + srow;      if (ra0 >= Mr) ra0 = Mr - 1;
  int ra1 = row0 + wave * 32 + srow + 16; if (ra1 >= Mr) ra1 = Mr - 1;
  const u16* pA0 = A + (size_t)ra0 * K + soct;
  const u16* pA1 = A + (size_t)ra1 * K + soct;
  const u16* pB0 = Bw + (size_t)(col0 + wave * 32 + srow) * K + soct;
  const u16* pB1 = pB0 + (size_t)16 * K;
  u16* dA0a = &lA0[(wave * 32) * 32];      u16* dA1a = &lA0[(wave * 32 + 16) * 32];
  u16* dA0b = &lA1[(wave * 32) * 32];      u16* dA1b = &lA1[(wave * 32 + 16) * 32];
  u16* dB0a = &lB0[(wave * 32) * 32];      u16* dB1a = &lB0[(wave * 32 + 16) * 32];
  u16* dB0b = &lB1[(wave * 32) * 32];      u16* dB1b = &lB1[(wave * 32 + 16) * 32];

  f32x4 acc[4][4];
#pragma unroll
  for (int i = 0; i < 4; ++i)
#pragma unroll
    for (int j = 0; j < 4; ++j) acc[i][j] = f32x4{0.f, 0.f, 0.f, 0.f};

  const int fr  = lane & 15;
  const int fo  = lane >> 4;
  const int lrd = fr * 32 + (((fo ^ ((fr >> 1) & 3))) << 3);
  const int ca  = (wr >> 4) * 512;
  const int cbb = (wc >> 4) * 512;

  for (int k0 = 0; k0 < K; k0 += 64) {
    __syncthreads();
    gll16(pA0 + k0, dA0a);       gll16(pA1 + k0, dA1a);
    gll16(pB0 + k0, dB0a);       gll16(pB1 + k0, dB1a);
    gll16(pA0 + k0 + 32, dA0b);  gll16(pA1 + k0 + 32, dA1b);
    gll16(pB0 + k0 + 32, dB0b);  gll16(pB1 + k0 + 32, dB1b);
    __syncthreads();

    bf16x8 af[4], bfr[4];
#pragma unroll
    for (int j = 0; j < 4; ++j)
      bfr[j] = *(const bf16x8*)&lB0[cbb + j * 512 + lrd];
#pragma unroll
    for (int i = 0; i < 4; ++i)
      af[i] = *(const bf16x8*)&lA0[ca + i * 512 + lrd];
#pragma unroll
    for (int i = 0; i < 4; ++i)
#pragma unroll
      for (int j = 0; j < 4; ++j)
        acc[i][j] = __builtin_amdgcn_mfma_f32_16x16x32_bf16(af[i], bfr[j], acc[i][j], 0, 0, 0);
#pragma unroll
    for (int j = 0; j < 4; ++j)
      bfr[j] = *(const bf16x8*)&lB1[cbb + j * 512 + lrd];
#pragma unroll
    for (int i = 0; i < 4; ++i)
      af[i] = *(const bf16x8*)&lA1[ca + i * 512 + lrd];
#pragma unroll
    for (int i = 0; i < 4; ++i)
#pragma unroll
      for (int j = 0; j < 4; ++j)
        acc[i][j] = __builtin_amdgcn_mfma_f32_16x16x32_bf16(af[i], bfr[j], acc[i][j], 0, 0, 0);
  }

  const int fc = lane & 15;
  const int rq = (lane >> 4) * 4;
#pragma unroll
  for (int i = 0; i < 4; ++i) {
#pragma unroll
    for (int j = 0; j < 4; ++j) {
      const int c = col0 + wc + j * 16 + fc;
      const float badd = bias0[c] + bias1[c];
#pragma unroll
      for (int reg = 0; reg < 4; ++reg) {
        int gr = row0 + wr + i * 16 + rq + reg;
        if (gr < Mr) {
          int bb = gr / sl, ss = gr - bb * sl;
          Cout[(size_t)(bb * RPB + obase + ss) * 1024 + c] = f2bf(acc[i][j][reg] + badd);
        }
      }
    }
  }
}

// ---------- windowed attention + mean over modalities ----------
// ROUTES (IEEE-tie-corrected Cantor): m0:[0,1,2] m1:[0,1,2] m2:[2,3,0] m3:[3,2,0]
__global__ __launch_bounds__(256) void attn_fuse(
    const u16* __restrict__ QKV,   // [RROWS][3072]: Q|K|V
    u16* __restrict__ fused,
    const float* __restrict__ bq, const float* __restrict__ bk, const float* __restrict__ bv,
    const float* __restrict__ temp_ptr)
{
  const int ROUTE[4][3] = {{0,1,2},{0,1,2},{2,3,0},{3,2,0}};
  const int SLm[4]  = {SL0, SL1, SL2, SL3};
  const int OFFS[4] = {0, 2048, 3072, 4572};
  const int tid  = threadIdx.x;
  const int lane = tid & 63;
  const int wave = tid >> 6;
  const int bs   = blockIdx.x * 2 + (wave >> 1);
  const int s    = bs & 2047;
  const int b    = bs >> 11;
  const int h    = (wave & 1) * 8 + (lane >> 3);
  const int sub  = lane & 7;
  const int dbase = h * 64 + sub * 8;
  const float scale = 1.0f / (8.0f * fabsf(temp_ptr[0]));

  float qf[4][8], kf[4][8], vf[4][8];
#pragma unroll
  for (int r = 0; r < 4; ++r) {
    if (s < SLm[r]) {
      const u16* base = QKV + ((size_t)(b * RPB + OFFS[r] + s)) * 3072 + dbase;
      u16x8 q8 = *(const u16x8*)(base);
      u16x8 k8 = *(const u16x8*)(base + 1024);
      u16x8 v8 = *(const u16x8*)(base + 2048);
#pragma unroll
      for (int i = 0; i < 8; ++i) {
        qf[r][i] = bf2f(q8[i]); kf[r][i] = bf2f(k8[i]); vf[r][i] = bf2f(v8[i]);
      }
    } else {
#pragma unroll
      for (int i = 0; i < 8; ++i) {
        qf[r][i] = bq[dbase + i]; kf[r][i] = bk[dbase + i]; vf[r][i] = bv[dbase + i];
      }
    }
  }

  float acc[8];
#pragma unroll
  for (int i = 0; i < 8; ++i) acc[i] = 0.f;

#pragma unroll
  for (int m = 0; m < 4; ++m) {
    float sc[3];
#pragma unroll
    for (int w = 0; w < 3; ++w) {
      const int r = ROUTE[m][w];
      float d = 0.f;
#pragma unroll
      for (int i = 0; i < 8; ++i) d += qf[m][i] * kf[r][i];
      d += __shfl_xor(d, 1, 64);
      d += __shfl_xor(d, 2, 64);
      d += __shfl_xor(d, 4, 64);
      sc[w] = d * scale;
    }
    float mx = fmaxf(sc[0], fmaxf(sc[1], sc[2]));
    float e0 = __expf(sc[0] - mx), e1 = __expf(sc[1] - mx), e2 = __expf(sc[2] - mx);
    float inv = 1.0f / (e0 + e1 + e2);
    float ws[3] = {e0 * inv, e1 * inv, e2 * inv};
#pragma unroll
    for (int w = 0; w < 3; ++w) {
      const int r = ROUTE[m][w];
#pragma unroll
      for (int i = 0; i < 8; ++i) acc[i] += ws[w] * vf[r][i];
    }
  }
  u16x8 o;
#pragma unroll
  for (int i = 0; i < 8; ++i) o[i] = f2bf(acc[i] * 0.25f);
  *(u16x8*)(fused + (size_t)bs * 1024 + dbase) = o;
}

// ---------- host orchestration ----------
extern "C" void kernel_launch(void* const* d_in, const int* in_sizes, int n_in,
                              void* d_out, int out_size, void* d_ws, size_t ws_size,
                              hipStream_t stream) {
  const int B = 4, S = 2048, D = 1024;
  const int SL[4]   = {SL0, SL1, SL2, SL3};
  const int DIM[4]  = {768, 1024, 512, 2048};
  const int OFFS[4] = {0, 2048, 3072, 4572};

  const float* x[4]  = {(const float*)d_in[0], (const float*)d_in[3], (const float*)d_in[6], (const float*)d_in[9]};
  const float* Wm[4] = {(const float*)d_in[1], (const float*)d_in[4], (const float*)d_in[7], (const float*)d_in[10]};
  const float* bm[4] = {(const float*)d_in[2], (const float*)d_in[5], (const float*)d_in[8], (const float*)d_in[11]};
  const float* mod_emb = (const float*)d_in[12];
  const float* Wq = (const float*)d_in[13]; const float* bq = (const float*)d_in[14];
  const float* Wk = (const float*)d_in[15]; const float* bk = (const float*)d_in[16];
  const float* Wv = (const float*)d_in[17]; const float* bv = (const float*)d_in[18];
  const float* Wo = (const float*)d_in[19]; const float* bo = (const float*)d_in[20];
  const float* temp = (const float*)d_in[21];

  const int RROWS = B * RPB;                 // 20336 real rows
  const size_t stackedB = ((size_t)RROWS * D * 2 + 255) / 256 * 256;
  const size_t qkvB     = ((size_t)RROWS * 3 * D * 2 + 255) / 256 * 256;
  const size_t wB       = ((size_t)D * D * 2 + 255) / 256 * 256;
  size_t wmB[4];
  for (int m = 0; m < 4; ++m) wmB[m] = ((size_t)D * DIM[m] * 2 + 255) / 256 * 256;
  const size_t need = stackedB + qkvB + 4 * wB + wmB[0] + wmB[1] + wmB[2] + wmB[3];
  if (ws_size < need) return;                // clean failure, not OOB crash

  char* p = (char*)d_ws;
  u16* stacked = (u16*)p;  p += stackedB;
  char* qkvbase = p;
  u16* qkv     = (u16*)p;  p += qkvB;
  u16* wqb     = (u16*)p;  p += wB;
  u16* wkb     = (u16*)p;  p += wB;
  u16* wvb     = (u16*)p;  p += wB;
  u16* wob     = (u16*)p;  p += wB;
  u16* wmb[4];
  for (int m = 0; m < 4; ++m) { wmb[m] = (u16*)p; p += wmB[m]; }
  u16* fusedb  = stacked;  // stacked dead after QKV GEMM

  // bf16 activations overlaid in the not-yet-live qkv buffer
  u16* xb[4];
  {
    char* q = qkvbase;
    for (int m = 0; m < 4; ++m) {
      xb[m] = (u16*)q;
      q += ((size_t)B * SL[m] * DIM[m] * 2 + 255) / 256 * 256;
    }
  }

  // single fused fp32->bf16 conversion
  {
    CvtSegs cs;
    const float* srcs[NSEG] = {x[0], x[1], x[2], x[3], Wm[0], Wm[1], Wm[2], Wm[3], Wq, Wk, Wv, Wo};
    u16* dsts[NSEG] = {xb[0], xb[1], xb[2], xb[3], wmb[0], wmb[1], wmb[2], wmb[3], wqb, wkb, wvb, wob};
    int ns[NSEG];
    for (int m = 0; m < 4; ++m) ns[m] = B * SL[m] * DIM[m];
    for (int m = 0; m < 4; ++m) ns[4 + m] = D * DIM[m];
    for (int i = 0; i < 4; ++i) ns[8 + i] = D * D;
    int base = 0;
    for (int i = 0; i < NSEG; ++i) {
      cs.src[i] = srcs[i]; cs.dst[i] = dsts[i];
      cs.blk_base[i] = base;
      base += (ns[i] + 1023) / 1024;
      cs.blk_end[i] = base;
    }
    cvt_multi<<<base, 256, 0, stream>>>(cs);
  }

  // ALL projections, one launch, longest-K segment first (video,image,text,audio)
  {
    const int ord[4] = {3, 1, 0, 2};   // by descending K: 2048,1024,768,512
    ProjSegs ps;
    int base = 0;
    for (int i = 0; i < 4; ++i) {
      int m = ord[i];
      int Mr = B * SL[m];
      ps.A[i] = xb[m]; ps.Bw[i] = wmb[m];
      ps.b0[i] = bm[m]; ps.b1[i] = mod_emb + m * D;
      ps.Mr[i] = Mr; ps.K[i] = DIM[m]; ps.sl[i] = SL[m]; ps.obase[i] = OFFS[m];
      base += 8 * ((Mr + 127) / 128);
      ps.blk_end[i] = base;
    }
    gemm_proj_all<<<base, 256, 0, stream>>>(ps, stacked);
  }

  // fused Q|K|V GEMM: [20336 x 3072] = stacked @ [Wq|Wk|Wv]^T
  {
    dim3 grid(12, (RROWS + 255) / 256);
    gemm_qkv_256<<<grid, 512, 0, stream>>>(stacked, wqb, wkb, wvb, bq, bk, bv,
                                           qkv, RROWS, D);
  }

  // attention over window + mean over modalities -> fused (bf16)
  attn_fuse<<<(B * S) / 2, 256, 0, stream>>>(qkv, fusedb, bq, bk, bv, temp);

  // output GEMM: (B*S) x D, fp32 out
  {
    dim3 grid(8, (B * S) / 128);
    gemm_lds<1><<<grid, 256, 0, stream>>>(fusedb, wob, wob, wob, bo, bo, bo,
                                          d_out, B * S, D, D);
  }
}